// Round 2
// baseline (633.252 us; speedup 1.0000x reference)
//
#include <hip/hip_runtime.h>

#define B_ 8
#define C_ 128
#define H_ 256
#define W_ 256
#define O_ 128
#define WT 128   // pixels per strip
#define RH 4     // rows per block

typedef __bf16 bf16x8 __attribute__((ext_vector_type(8)));
typedef float floatx4 __attribute__((ext_vector_type(4)));

// s_lds layout: row p (128 bf16 = 8 blocks of 16B), block index xor-swizzled by (p&7).
// addr(p, c) = p*128 + (((c>>3) ^ (p&7))<<3) + (c&7)   -- c accessed in aligned groups of 8.

__global__ __launch_bounds__(256, 3)
void activeshift_kernel(const float* __restrict__ x,
                        const float* __restrict__ theta,
                        const float* __restrict__ wdw,
                        const float* __restrict__ wpw,
                        float* __restrict__ out)
{
    __shared__ __align__(16) __bf16 s_lds[WT * 128];
    __shared__ int4 t_lds[C_];

    const int n     = blockIdx.x;
    const int strip = n & 1;
    const int hb    = (n >> 1) & (H_/RH - 1);   // 64 row-blocks
    const int b     = n >> 7;
    const int w0    = strip * WT;
    const int h0    = hb * RH;
    const int tid   = threadIdx.x;

    // ---- per-channel shift decomposition (once per block) ----
    if (tid < C_) {
        float t0 = -theta[tid * 2 + 0];
        float t1 = -theta[tid * 2 + 1];
        float f0 = floorf(t0), f1 = floorf(t1);
        int4 v;
        v.x = (int)f0;
        v.y = (int)f1;
        v.z = __float_as_int(t0 - f0);
        v.w = __float_as_int(t1 - f1);
        t_lds[tid] = v;
    }

    // ---- A fragments (w_eff = w_pw * w_dw) held in registers for whole block ----
    const int wid  = tid >> 6;
    const int lane = tid & 63;
    const int wo   = (wid >> 1) * 64;   // o base of this wave
    const int wpx  = (wid & 1) * 64;    // pixel base of this wave
    const int l15  = lane & 15;
    const int quad = lane >> 4;

    bf16x8 afrag[4][4];   // [kstep][i]; A[m=o][k=c]: m=lane&15, k=quad*8+j
    #pragma unroll
    for (int ks = 0; ks < 4; ++ks) {
        int cb = ks * 32 + quad * 8;
        float4 da = *(const float4*)(wdw + cb);
        float4 db = *(const float4*)(wdw + cb + 4);
        #pragma unroll
        for (int i = 0; i < 4; ++i) {
            int o = wo + i * 16 + l15;
            float4 wa = *(const float4*)(wpw + o * C_ + cb);
            float4 wb = *(const float4*)(wpw + o * C_ + cb + 4);
            bf16x8 f;
            f[0] = (__bf16)(wa.x * da.x); f[1] = (__bf16)(wa.y * da.y);
            f[2] = (__bf16)(wa.z * da.z); f[3] = (__bf16)(wa.w * da.w);
            f[4] = (__bf16)(wb.x * db.x); f[5] = (__bf16)(wb.y * db.y);
            f[6] = (__bf16)(wb.z * db.z); f[7] = (__bf16)(wb.w * db.w);
            afrag[ks][i] = f;
        }
    }

    const int p    = tid & (WT - 1);
    const int half = tid >> 7;          // wave-uniform
    const float* xb = x + (size_t)b * (C_ * H_ * W_);
    const size_t HW = (size_t)H_ * W_;

    __syncthreads();

    for (int hr = 0; hr < RH; ++hr) {
        const int h = h0 + hr;

        // ---- stage s: 1 pixel x 8 consecutive channels -> one ds_write_b128 ----
        for (int it = 0; it < 8; ++it) {
            int c0 = it * 16 + half * 8;
            union { bf16x8 v; __bf16 e[8]; } pk;
            #pragma unroll
            for (int cc = 0; cc < 8; ++cc) {
                int c = c0 + cc;
                int4 tv = t_lds[c];                 // broadcast read
                float dy = __int_as_float(tv.z);
                float dx = __int_as_float(tv.w);
                int Y0 = h + tv.x;                  // unpadded row of v00
                int X0 = w0 + p + tv.y;             // unpadded col of v00
                int Yc0 = min(max(Y0, 0), H_ - 1);
                int Yc1 = min(max(Y0 + 1, 0), H_ - 1);
                int Xc0 = min(max(X0, 0), W_ - 1);
                int Xc1 = min(max(X0 + 1, 0), W_ - 1);
                bool ry0 = (unsigned)Y0 < (unsigned)H_;
                bool ry1 = (unsigned)(Y0 + 1) < (unsigned)H_;
                bool cx0 = (unsigned)X0 < (unsigned)W_;
                bool cx1 = (unsigned)(X0 + 1) < (unsigned)W_;
                const float* cbase = xb + (size_t)c * HW;   // wave-uniform base
                int r0o = Yc0 * W_, r1o = Yc1 * W_;
                float v00 = cbase[r0o + Xc0];   // clamped-safe unconditional loads
                float v01 = cbase[r0o + Xc1];
                float v10 = cbase[r1o + Xc0];
                float v11 = cbase[r1o + Xc1];
                v00 = (ry0 && cx0) ? v00 : 0.0f;
                v01 = (ry0 && cx1) ? v01 : 0.0f;
                v10 = (ry1 && cx0) ? v10 : 0.0f;
                v11 = (ry1 && cx1) ? v11 : 0.0f;
                float r0 = v00 + dx * (v01 - v00);
                float r1 = v10 + dx * (v11 - v10);
                pk.e[cc] = (__bf16)(r0 + dy * (r1 - r0));
            }
            int blk = (it * 2 + half) ^ (p & 7);    // xor swizzle
            *(bf16x8*)&s_lds[p * 128 + blk * 8] = pk.v;
        }
        __syncthreads();

        // ---- GEMM: out[o, pix] = sum_c w_eff[o,c] * s[c,pix] ----
        floatx4 acc[4][4];
        #pragma unroll
        for (int i = 0; i < 4; ++i)
            #pragma unroll
            for (int j = 0; j < 4; ++j)
                acc[i][j] = (floatx4){0.f, 0.f, 0.f, 0.f};

        #pragma unroll
        for (int ks = 0; ks < 4; ++ks) {
            bf16x8 bfr[4];
            #pragma unroll
            for (int j = 0; j < 4; ++j) {   // B[k=c][n=pix]: n=lane&15, k=quad*8+jj
                int np = wpx + j * 16 + l15;
                int blk = (ks * 4 + quad) ^ (np & 7);
                bfr[j] = *(const bf16x8*)&s_lds[np * 128 + blk * 8];
            }
            #pragma unroll
            for (int i = 0; i < 4; ++i)
                #pragma unroll
                for (int j = 0; j < 4; ++j)
                    acc[i][j] = __builtin_amdgcn_mfma_f32_16x16x32_bf16(afrag[ks][i], bfr[j], acc[i][j], 0, 0, 0);
        }

        // ---- store: D col = lane&15 = pixel, row = quad*4+reg = o ----
        float* ob = out + (size_t)b * O_ * HW + (size_t)h * W_;
        #pragma unroll
        for (int i = 0; i < 4; ++i) {
            #pragma unroll
            for (int j = 0; j < 4; ++j) {
                int pcol  = w0 + wpx + j * 16 + l15;
                int obase = wo + i * 16 + quad * 4;
                float* op = ob + (size_t)obase * HW + pcol;
                #pragma unroll
                for (int r = 0; r < 4; ++r)
                    op[(size_t)r * HW] = acc[i][j][r];
            }
        }
        __syncthreads();   // s_lds reused next row
    }
}

extern "C" void kernel_launch(void* const* d_in, const int* in_sizes, int n_in,
                              void* d_out, int out_size, void* d_ws, size_t ws_size,
                              hipStream_t stream) {
    const float* x     = (const float*)d_in[0];
    const float* theta = (const float*)d_in[1];
    const float* wdw   = (const float*)d_in[2];
    const float* wpw   = (const float*)d_in[3];
    float* out = (float*)d_out;
    dim3 grid(B_ * (H_ / RH) * (W_ / WT));   // 1024 workgroups
    activeshift_kernel<<<grid, dim3(256), 0, stream>>>(x, theta, wdw, wpw, out);
}